// Round 8
// baseline (159.513 us; speedup 1.0000x reference)
//
#include <hip/hip_runtime.h>
#include <hip/hip_bf16.h>

#define N_    16
#define IC_   512
#define OC_   512
#define SDIM_ 512
#define H_    32
#define W_    32
#define HW_   1024

#define FC_SCALER 0.04419417382415922f          /* 1/sqrt(512) */
#define WS_       0.014731391274719738f         /* 1/sqrt(4608) */
#define WS2_      (1.0f/4608.0f)

typedef __attribute__((__ext_vector_type__(8)))  __bf16 bf16x8;
typedef __attribute__((__ext_vector_type__(16))) float  f32x16;
typedef __attribute__((__ext_vector_type__(4)))  int    i32x4;

#define LGKM0()  asm volatile("s_waitcnt lgkmcnt(0)" ::: "memory")
#define SB()     __builtin_amdgcn_sched_barrier(0)

__device__ __forceinline__ unsigned short f2bf(float f) {
    unsigned int u = __builtin_bit_cast(unsigned int, f);
    unsigned int r = (u + 0x7FFFu + ((u >> 16) & 1u)) >> 16;
    return (unsigned short)r;
}

// ---------------- K1: mod[n][c] = style[n]·fcw[c]*FC_SCALER + fcb[c] + 1 ----------------
__global__ void k_mod(const float* __restrict__ style, const float* __restrict__ fcw,
                      const float* __restrict__ fcb, float* __restrict__ mod) {
    int gid = blockIdx.x * blockDim.x + threadIdx.x;
    int wid = gid >> 6, lane = gid & 63;
    if (wid >= N_ * IC_) return;
    int n = wid >> 9, c = wid & 511;
    const float4* sp = (const float4*)(style + n * SDIM_);
    const float4* wp = (const float4*)(fcw + (size_t)c * SDIM_);
    float acc = 0.f;
    for (int i = lane; i < SDIM_ / 4; i += 64) {
        float4 a = sp[i], b = wp[i];
        acc += a.x*b.x + a.y*b.y + a.z*b.z + a.w*b.w;
    }
#pragma unroll
    for (int off = 32; off; off >>= 1) acc += __shfl_xor(acc, off);
    if (lane == 0) mod[wid] = acc * FC_SCALER + fcb[c] + 1.0f;
}

// ---------------- K2: wt k-major: [tap][og8][icc16][ks4][ocl64][8ic] --------------------
__global__ void k_wprep(const float* __restrict__ w, unsigned short* __restrict__ wt,
                        float* __restrict__ wsq) {
    int tid = blockIdx.x * blockDim.x + threadIdx.x;   // 0 .. OC*IC-1
    int oc = tid >> 9, ic = tid & 511;
    int og = oc >> 6, ocl = oc & 63;
    int icc = ic >> 5, ks = (ic >> 3) & 3, i8 = ic & 7;
    float s = 0.f;
#pragma unroll
    for (int t = 0; t < 9; t++) {
        float v = w[(size_t)tid * 9 + t];
        s += v * v;
        size_t off = (((size_t)t * 8 + og) * 16 + icc) * 2048
                   + (size_t)ks * 512 + ocl * 8 + i8;
        wt[off] = f2bf(v);
    }
    wsq[tid] = s;
}

// ---------------- K3: demod_ws[n][oc] = WS * rsqrt(WS2*sum_ic mod^2*wsq + 1e-8) ---------
__global__ void k_demod(const float* __restrict__ mod, const float* __restrict__ wsq,
                        float* __restrict__ demod_ws) {
    int gid = blockIdx.x * blockDim.x + threadIdx.x;
    int wid = gid >> 6, lane = gid & 63;
    if (wid >= N_ * OC_) return;
    int n = wid >> 9, oc = wid & 511;
    const float4* mp = (const float4*)(mod + n * IC_);
    const float4* qp = (const float4*)(wsq + (size_t)oc * IC_);
    float acc = 0.f;
    for (int i = lane; i < IC_ / 4; i += 64) {
        float4 m = mp[i], q = qp[i];
        acc += m.x*m.x*q.x + m.y*m.y*q.y + m.z*m.z*q.z + m.w*m.w*q.w;
    }
#pragma unroll
    for (int off = 32; off; off >>= 1) acc += __shfl_xor(acc, off);
    if (lane == 0) {
        float s = WS2_ * acc + 1e-8f;
        demod_ws[wid] = WS_ / sqrtf(s);
    }
}

// ---------------- K4 (fused conv): implicit-GEMM, bf16 MFMA 32x32x16 --------------------
// grid 512 (n-major XCD swizzle), block 256 thr = 4 waves (kh2 x wc2), 2 blocks/CU.
// Block tile 64oc x 256sp (8 rows) x 32ic; wave 64oc x 128sp (4 rows) x 16ic (kh split).
// A (weights): DIRECT global->VGPR ping-pong, 1 phase ahead (off the LDS pipe; L1/L2).
// B (x*mod): fp32 global -> regs -> cvt_pk bf16 -> ds_write; LDS dbuf; reads 6/wave/phase.
// Sync: ONE raw s_barrier + lgkmcnt(0) per icc; all vm waits compiler-managed (reg dests).
// Epilogue kh-exchange: per-fo two-pass, 32KB compact index (fits smem; R7 bug was 64KB OOB).
__global__ __launch_bounds__(256, 2)
void k_conv(const float* __restrict__ x, const float* __restrict__ mod,
            const unsigned short* __restrict__ wt,
            const float* __restrict__ demod_ws, float* __restrict__ out) {
    __shared__ __align__(16) char smem[43360];
    // xt[2] @0 (2x20480=40960), zslot @40960 (32), s_demod @40992 (256), mod_lds @41248(2048)
    unsigned short* xt0     = (unsigned short*)(smem);
    float*          zslot   = (float*)(smem + 40960);
    float*          s_demod = (float*)(smem + 40992);
    float*          mod_lds = (float*)(smem + 41248);

    int bx = blockIdx.x;
    // n-major XCD grouping: XCD (bx%8) hosts 2 n's -> x/w L2 locality
    int x8 = bx & 7, jj = bx >> 3;              // jj 0..63
    int n = x8 * 2 + (jj >> 5);
    int rem = jj & 31;
    int octg = rem >> 2, spt = rem & 3;
    int oc0 = octg * 64, y0 = spt * 8;

    int tid = threadIdx.x, lane = tid & 63, wid = tid >> 6;
    int l31 = lane & 31, lhi = lane >> 5;
    int wc = wid & 1, kh = wid >> 1;
    int kso = kh * 2 + lhi;                     // per-lane k-slot (8 ic)

    if (tid < 64) s_demod[tid] = demod_ws[n * OC_ + oc0 + tid];
    if (tid < 128) ((float4*)mod_lds)[tid] = ((const float4*)(mod + n * IC_))[tid];
    if (tid == 0) { i32x4 z = {}; *(i32x4*)zslot = z; }

    const float* xsrc = x + (size_t)n * IC_ * HW_;

    // ---- x reg staging: thread = (ks=wid, col=l31), rows rr = lhi+2k, 8 ic each ----
    float xr[5][8];
    auto stage_xregs = [&](int icc) {
#pragma unroll
        for (int k = 0; k < 5; k++) {
            int rr = lhi + 2 * k;
            int y = y0 - 1 + rr;
            int yc = y < 0 ? 0 : (y > 31 ? 31 : y);
            const float* base = xsrc + ((size_t)(icc * 32 + wid * 8)) * HW_ + yc * 32 + l31;
#pragma unroll
            for (int i = 0; i < 8; i++) xr[k][i] = base[(size_t)i * HW_];
        }
    };
    // cvt xr (holding x(icct)) -> xt[buf]; oob rows write zeros
    auto cvt_store = [&](int icct, int buf) {
        int mi = (icct & 15) * 32 + wid * 8;
        float4 mA = *(const float4*)&mod_lds[mi];
        float4 mB = *(const float4*)&mod_lds[mi + 4];
#pragma unroll
        for (int k = 0; k < 5; k++) {
            int rr = lhi + 2 * k;
            int y = y0 - 1 + rr;
            bool oob = (unsigned)y >= 32u;
            unsigned r0 = 0, r1 = 0, r2 = 0, r3 = 0;
            if (!oob) {
                float f0 = xr[k][0]*mA.x, f1 = xr[k][1]*mA.y;
                float f2 = xr[k][2]*mA.z, f3 = xr[k][3]*mA.w;
                float f4 = xr[k][4]*mB.x, f5 = xr[k][5]*mB.y;
                float f6 = xr[k][6]*mB.z, f7 = xr[k][7]*mB.w;
                asm("v_cvt_pk_bf16_f32 %0, %1, %2" : "=v"(r0) : "v"(f0), "v"(f1));
                asm("v_cvt_pk_bf16_f32 %0, %1, %2" : "=v"(r1) : "v"(f2), "v"(f3));
                asm("v_cvt_pk_bf16_f32 %0, %1, %2" : "=v"(r2) : "v"(f4), "v"(f5));
                asm("v_cvt_pk_bf16_f32 %0, %1, %2" : "=v"(r3) : "v"(f6), "v"(f7));
            }
            i32x4 v = { (int)r0, (int)r1, (int)r2, (int)r3 };
            *(i32x4*)(xt0 + buf * 10240 + rr * 1024 + wid * 256 + l31 * 8) = v;
        }
    };
    // A-frags for global phase g2: 6 x global_load_dwordx4 (L1/L2), compiler-managed waits
    auto fetch_w = [&](int g2, bf16x8 (&dst)[6]) {
        int gc = g2 < 48 ? g2 : 47;
        int icc2 = gc / 3, p2 = gc - icc2 * 3;
#pragma unroll
        for (int dy = 0; dy < 3; dy++) {
            int tap = dy * 3 + p2;
            const unsigned short* base =
                wt + (((size_t)tap * 8 + octg) * 16 + icc2) * 2048 + kso * 512 + l31 * 8;
            dst[dy * 2 + 0] = *(const bf16x8*)(base);
            dst[dy * 2 + 1] = *(const bf16x8*)(base + 256);
        }
    };

    f32x16 acc[2][4] = {};
    int xb = 0;

    auto compute = [&](int p, const bf16x8 (&wAv)[6]) {
        const unsigned short* xtb = xt0 + xb * 10240;
        int col = l31 + p - 1;
        bool oobc = (unsigned)col >= 32u;
        bf16x8 r6[6];
#pragma unroll
        for (int j = 0; j < 6; j++) {
            int rr = wc * 4 + j;
            const unsigned short* src = oobc ? (const unsigned short*)zslot
                : xtb + rr * 1024 + kso * 256 + col * 8;
            r6[j] = *(const bf16x8*)src;
        }
#pragma unroll
        for (int dy = 0; dy < 3; dy++) {
            __builtin_amdgcn_s_setprio(1);
#pragma unroll
            for (int fs = 0; fs < 4; fs++)
                acc[0][fs] = __builtin_amdgcn_mfma_f32_32x32x16_bf16(
                    wAv[dy * 2 + 0], r6[fs + dy], acc[0][fs], 0, 0, 0);
#pragma unroll
            for (int fs = 0; fs < 4; fs++)
                acc[1][fs] = __builtin_amdgcn_mfma_f32_32x32x16_bf16(
                    wAv[dy * 2 + 1], r6[fs + dy], acc[1][fs], 0, 0, 0);
            __builtin_amdgcn_s_setprio(0);
        }
    };

    bf16x8 wA0[6], wA1[6];

    // ---- prologue ----
    stage_xregs(0);
    fetch_w(0, wA0);
    __syncthreads();              // mod_lds / zslot visible (full drain once, ok)
    cvt_store(0, 0);              // x(0) -> xt[0]
    stage_xregs(1);
    LGKM0();
    __builtin_amdgcn_s_barrier(); // xt[0] visible
    SB();

    // one icc: compute g0 from sA; fetch g0+1->sB (p0), g0+2->sA (p0), g0+3->sB (p1).
    auto icc_body = [&](int icc, bf16x8 (&sA)[6], bf16x8 (&sB)[6]) {
        int g0 = icc * 3;
        fetch_w(g0 + 1, sB);
        compute(0, sA);
        fetch_w(g0 + 2, sA);
        if (icc < 15) cvt_store(icc + 1, xb ^ 1);
        stage_xregs(icc + 2 <= 15 ? icc + 2 : 0);
        compute(1, sB);
        fetch_w(g0 + 3, sB);
        compute(2, sA);
        LGKM0();
        __builtin_amdgcn_s_barrier();
        SB();
        xb ^= 1;
    };

#pragma unroll 1
    for (int ii = 0; ii < 8; ii++) {
        icc_body(2 * ii,     wA0, wA1);
        icc_body(2 * ii + 1, wA1, wA0);
    }

    // ---- epilogue: combine kh halves, per-fo two-pass 32KB exchange (fits smem) ----
    __syncthreads();
    float* exch = (float*)smem;               // aliases xt region only (<= 32KB used)
#pragma unroll
    for (int fo = 0; fo < 2; fo++) {
        if (kh == 1) {
#pragma unroll
            for (int fs = 0; fs < 4; fs++)
#pragma unroll
                for (int rg = 0; rg < 16; rg++)
                    exch[((wc * 4 + fs) * 16 + rg) * 64 + lane] = acc[fo][fs][rg];
        }
        __syncthreads();
        if (kh == 0) {
#pragma unroll
            for (int fs = 0; fs < 4; fs++) {
                int y = y0 + wc * 4 + fs;
#pragma unroll
                for (int rg = 0; rg < 16; rg++) {
                    int row = (rg & 3) + 8 * (rg >> 2) + 4 * lhi;
                    int ocl = fo * 32 + row;
                    float v = acc[fo][fs][rg]
                            + exch[((wc * 4 + fs) * 16 + rg) * 64 + lane];
                    v *= s_demod[ocl];
                    out[((size_t)(n * OC_ + oc0 + ocl) * H_ + y) * W_ + l31] = v;
                }
            }
        }
        __syncthreads();
    }
}

extern "C" void kernel_launch(void* const* d_in, const int* in_sizes, int n_in,
                              void* d_out, int out_size, void* d_ws, size_t ws_size,
                              hipStream_t stream) {
    const float* x      = (const float*)d_in[0];
    const float* style  = (const float*)d_in[1];
    const float* weight = (const float*)d_in[2];
    const float* fcw    = (const float*)d_in[3];
    const float* fcb    = (const float*)d_in[4];
    float* out = (float*)d_out;

    char* ws = (char*)d_ws;
    float*          mod   = (float*)ws;                          // 32 KB
    float*          demod = (float*)(ws + 32768);                // 32 KB
    float*          wsq   = (float*)(ws + 65536);                // 1 MB
    unsigned short* wtb   = (unsigned short*)(ws + 65536 + 1048576);           // 4.5 MB

    k_mod   <<<2048, 256, 0, stream>>>(style, fcw, fcb, mod);
    k_wprep <<<1024, 256, 0, stream>>>(weight, wtb, wsq);
    k_demod <<<2048, 256, 0, stream>>>(mod, wsq, demod);
    k_conv  <<<512,  256, 0, stream>>>(x, mod, wtb, demod, out);
}